// Round 6
// baseline (135.984 us; speedup 1.0000x reference)
//
#include <hip/hip_runtime.h>
#include <hip/hip_cooperative_groups.h>

namespace cg = cooperative_groups;

#define NN 4096
#define BB 4
#define EE 256
#define DD 64
#define SCALE 0.125f
#define NBLK 128   // blocks per batch row
#define RB 32      // rows per block
#define RW 8       // rows per wave (fully unrolled -> 8 gathers in flight)

// Single cooperative kernel, grid (NBLK, BB) x 256 threads.
// Phase 1: gather ev[r]=embed[pos[i]] (KEPT IN REGISTERS), u_blk[e], V_blk;
//          partial s_blk[d] = sum_e u_blk[e]*Wq[d,e] + bq[d]*V_blk -> part_s
// grid.sync()
// Phase 2: s[d] = sum_blk part_s; w[e] = sum_d s[d]*Wk[d,e]; c = s.bk
// Phase 3: out[b,j] = val[b,j]*(1 + SCALE*(ev[j].w + c))   (ev from regs)
__global__ __launch_bounds__(256) void k_all(
        const float* __restrict__ val, const int* __restrict__ pos,
        const float* __restrict__ embed,
        const float* __restrict__ Wq, const float* __restrict__ bq,
        const float* __restrict__ Wk, const float* __restrict__ bk,
        float* __restrict__ part_s, float* __restrict__ out) {
    const int b    = blockIdx.y;
    const int bx   = blockIdx.x;
    const int t    = threadIdx.x;
    const int lane = t & 63;
    const int wv   = t >> 6;
    const int seg  = wv;             // e-segment / blk-segment id
    const int base = b * NN + bx * RB + wv * RW;

    __shared__ float plds[4][EE];
    __shared__ float vlds[4];
    __shared__ float uS[EE];
    __shared__ float ps[4][DD];
    __shared__ float sS[DD];
    __shared__ float wsh[EE];
    __shared__ float rowres[RB];
    __shared__ float cSh;

    // ---- Phase 1a: gather embed rows, keep in registers ----
    float v[RW]; int p[RW];
    #pragma unroll
    for (int r = 0; r < RW; ++r) { v[r] = val[base + r]; p[r] = pos[base + r]; }

    float4 ev[RW];
    #pragma unroll
    for (int r = 0; r < RW; ++r)
        ev[r] = reinterpret_cast<const float4*>(embed + (size_t)p[r] * EE)[lane];

    float4 acc = make_float4(0.f, 0.f, 0.f, 0.f);
    float vs = 0.f;
    #pragma unroll
    for (int r = 0; r < RW; ++r) {
        acc.x += v[r] * ev[r].x; acc.y += v[r] * ev[r].y;
        acc.z += v[r] * ev[r].z; acc.w += v[r] * ev[r].w;
        vs += v[r];
    }
    *reinterpret_cast<float4*>(&plds[wv][4 * lane]) = acc;
    if (lane == 0) vlds[wv] = vs;
    __syncthreads();
    uS[t] = plds[0][t] + plds[1][t] + plds[2][t] + plds[3][t];
    __syncthreads();

    // ---- Phase 1b: partial s_blk[d] via Wq matvec on this block's u_blk ----
    {
        const int d = lane;
        const float4* uu = reinterpret_cast<const float4*>(&uS[seg * 64]);
        const float4* wq = reinterpret_cast<const float4*>(Wq + (size_t)d * EE + seg * 64);
        float a = 0.f;
        #pragma unroll
        for (int q = 0; q < 16; ++q) {
            const float4 x = uu[q], y = wq[q];
            a += x.x * y.x + x.y * y.y + x.z * y.z + x.w * y.w;
        }
        ps[seg][d] = a;
    }
    __syncthreads();
    if (t < DD) {
        const float Vblk = vlds[0] + vlds[1] + vlds[2] + vlds[3];
        part_s[((size_t)b * NBLK + bx) * DD + t] =
            ps[0][t] + ps[1][t] + ps[2][t] + ps[3][t] + bq[t] * Vblk;
    }

    cg::this_grid().sync();

    // ---- Phase 2: reduce part_s -> s; then w, c ----
    {
        const int d = lane;
        const float* pp = part_s + ((size_t)b * NBLK + seg * 32) * DD + d;
        float a = 0.f;
        #pragma unroll 8
        for (int i = 0; i < 32; ++i) a += pp[(size_t)i * DD];
        ps[seg][d] = a;
    }
    __syncthreads();
    if (t < DD) sS[t] = ps[0][t] + ps[1][t] + ps[2][t] + ps[3][t];
    __syncthreads();

    if (wv == 0) {
        float x = sS[lane] * bk[lane];
        #pragma unroll
        for (int off = 32; off; off >>= 1) x += __shfl_down(x, off, 64);
        if (lane == 0) cSh = x;
    }
    {
        float a = 0.f;
        #pragma unroll
        for (int d = 0; d < DD; ++d) a += sS[d] * Wk[d * EE + t];  // coalesced in t
        wsh[t] = a;
    }
    __syncthreads();

    // ---- Phase 3: per-row dot from registers, shfl reduce, coalesced store ----
    const float4 wf = reinterpret_cast<const float4*>(wsh)[lane];
    #pragma unroll
    for (int r = 0; r < RW; ++r) {
        float a = ev[r].x * wf.x + ev[r].y * wf.y + ev[r].z * wf.z + ev[r].w * wf.w;
        #pragma unroll
        for (int off = 32; off; off >>= 1) a += __shfl_down(a, off, 64);
        if (lane == 0) rowres[wv * RW + r] = a;
    }
    __syncthreads();
    if (t < RB) {
        const int j = bx * RB + t;
        const float vv = val[b * NN + j];
        out[b * NN + j] = vv * (1.f + SCALE * (rowres[t] + cSh));
    }
}

extern "C" void kernel_launch(void* const* d_in, const int* in_sizes, int n_in,
                              void* d_out, int out_size, void* d_ws, size_t ws_size,
                              hipStream_t stream) {
    // inputs: t(0), val(1), pos(2), embed(3), Wq(4), bq(5), Wk(6), bk(7)
    const float* val   = (const float*)d_in[1];
    const int*   pos   = (const int*)d_in[2];
    const float* embed = (const float*)d_in[3];
    const float* Wq    = (const float*)d_in[4];
    const float* bq    = (const float*)d_in[5];
    const float* Wk    = (const float*)d_in[6];
    const float* bk    = (const float*)d_in[7];
    float* out    = (float*)d_out;
    float* part_s = (float*)d_ws;   // BB*NBLK*DD floats = 128 KB, fully overwritten

    void* args[] = { (void*)&val, (void*)&pos, (void*)&embed,
                     (void*)&Wq, (void*)&bq, (void*)&Wk, (void*)&bk,
                     (void*)&part_s, (void*)&out };
    dim3 grid(NBLK, BB);   // 512 blocks, 2 per CU -> co-resident
    hipLaunchCooperativeKernel((const void*)k_all, grid, dim3(256), args, 0, stream);
}

// Round 7
// 87.681 us; speedup vs baseline: 1.5509x; 1.5509x over previous
//
#include <hip/hip_runtime.h>

#define NN 4096
#define BB 4
#define EE 256
#define DD 64
#define SCALE 0.125f
#define NBLK 128   // blocks per batch row
#define RB 32      // rows per block
#define RW 8       // rows per wave (fully unrolled -> 8 gathers in flight)

// ---------------- Kernel 1 ----------------
// Per block: u_blk[e] = sum_{i in blk} val[i]*embed[pos[i],e]; V_blk = sum val
// Fold Wq here:  part_s[b,blk,d] = sum_e u_blk[e]*Wq[d,e] + bq[d]*V_blk
// (64 floats/block; no atomics; every slot overwritten -> no zero-init)
__global__ __launch_bounds__(256) void k_accum(
        const float* __restrict__ val, const int* __restrict__ pos,
        const float* __restrict__ embed,
        const float* __restrict__ Wq, const float* __restrict__ bq,
        float* __restrict__ part_s) {
    const int b = blockIdx.y, bx = blockIdx.x, t = threadIdx.x;
    const int lane = t & 63, wv = t >> 6, seg = wv;
    const int base = b * NN + bx * RB + wv * RW;

    __shared__ float plds[4][EE];
    __shared__ float vlds[4];
    __shared__ float uS[EE];
    __shared__ float ps[4][DD];

    float v[RW]; int p[RW];
    #pragma unroll
    for (int r = 0; r < RW; ++r) { v[r] = val[base + r]; p[r] = pos[base + r]; }

    float4 acc = make_float4(0.f, 0.f, 0.f, 0.f);
    float vs = 0.f;
    #pragma unroll
    for (int r = 0; r < RW; ++r) {
        const float4 ev = reinterpret_cast<const float4*>(embed + (size_t)p[r] * EE)[lane];
        acc.x += v[r] * ev.x; acc.y += v[r] * ev.y;
        acc.z += v[r] * ev.z; acc.w += v[r] * ev.w;
        vs += v[r];
    }
    *reinterpret_cast<float4*>(&plds[wv][4 * lane]) = acc;
    if (lane == 0) vlds[wv] = vs;
    __syncthreads();
    uS[t] = plds[0][t] + plds[1][t] + plds[2][t] + plds[3][t];
    __syncthreads();

    // Wq fold: thread (seg, d=lane) sums a 64-wide e-segment, float4 loads
    {
        const float4* uu = reinterpret_cast<const float4*>(&uS[seg * 64]);
        const float4* wq = reinterpret_cast<const float4*>(Wq + (size_t)lane * EE + seg * 64);
        float a = 0.f;
        #pragma unroll
        for (int q = 0; q < 16; ++q) {
            const float4 x = uu[q], y = wq[q];
            a += x.x * y.x + x.y * y.y + x.z * y.z + x.w * y.w;
        }
        ps[seg][lane] = a;
    }
    __syncthreads();
    if (t < DD) {
        const float Vblk = vlds[0] + vlds[1] + vlds[2] + vlds[3];
        part_s[((size_t)b * NBLK + bx) * DD + t] =
            ps[0][t] + ps[1][t] + ps[2][t] + ps[3][t] + bq[t] * Vblk;
    }
}

// ---------------- Kernel 2 ----------------
// Issue embed gathers into registers FIRST (latency hides under the reduce),
// then: s[d] = sum_blk part_s[b,blk,d];  w[e] = sum_d s[d]*Wk[d,e];  c = s.bk
// then: out[b,j] = val[b,j]*(1 + SCALE*(ev[j].w + c))
__global__ __launch_bounds__(256) void k_out(
        const float* __restrict__ val, const int* __restrict__ pos,
        const float* __restrict__ embed,
        const float* __restrict__ part_s,
        const float* __restrict__ Wk, const float* __restrict__ bk,
        float* __restrict__ out) {
    const int b = blockIdx.y, bx = blockIdx.x, t = threadIdx.x;
    const int lane = t & 63, wv = t >> 6, seg = wv;
    const int base = b * NN + bx * RB + wv * RW;

    __shared__ float ps[4][DD];
    __shared__ float sS[DD];
    __shared__ float wsh[EE];
    __shared__ float rowres[RB];
    __shared__ float cSh;

    // ---- issue gathers early; results consumed in phase C ----
    int p[RW];
    #pragma unroll
    for (int r = 0; r < RW; ++r) p[r] = pos[base + r];
    float4 ev[RW];
    #pragma unroll
    for (int r = 0; r < RW; ++r)
        ev[r] = reinterpret_cast<const float4*>(embed + (size_t)p[r] * EE)[lane];

    // ---- A0: reduce part_s -> sS (L2-hot, coalesced within wave) ----
    {
        const float* pp = part_s + ((size_t)b * NBLK + seg * 32) * DD + lane;
        float a = 0.f;
        #pragma unroll 8
        for (int i = 0; i < 32; ++i) a += pp[(size_t)i * DD];
        ps[seg][lane] = a;
    }
    __syncthreads();
    if (t < DD) sS[t] = ps[0][t] + ps[1][t] + ps[2][t] + ps[3][t];
    __syncthreads();

    // ---- B: c (wave 0) and w[e] (all threads, coalesced in t) ----
    if (wv == 0) {
        float x = sS[lane] * bk[lane];
        #pragma unroll
        for (int off = 32; off; off >>= 1) x += __shfl_down(x, off, 64);
        if (lane == 0) cSh = x;
    }
    {
        float a = 0.f;
        #pragma unroll
        for (int d = 0; d < DD; ++d) a += sS[d] * Wk[d * EE + t];
        wsh[t] = a;
    }
    __syncthreads();

    // ---- C: per-row dot from registers, shfl reduce, coalesced store ----
    const float4 wf = reinterpret_cast<const float4*>(wsh)[lane];
    #pragma unroll
    for (int r = 0; r < RW; ++r) {
        float a = ev[r].x * wf.x + ev[r].y * wf.y + ev[r].z * wf.z + ev[r].w * wf.w;
        #pragma unroll
        for (int off = 32; off; off >>= 1) a += __shfl_down(a, off, 64);
        if (lane == 0) rowres[wv * RW + r] = a;
    }
    __syncthreads();
    if (t < RB) {
        const int j = bx * RB + t;
        const float vv = val[b * NN + j];
        out[b * NN + j] = vv * (1.f + SCALE * (rowres[t] + cSh));
    }
}

extern "C" void kernel_launch(void* const* d_in, const int* in_sizes, int n_in,
                              void* d_out, int out_size, void* d_ws, size_t ws_size,
                              hipStream_t stream) {
    // inputs: t(0), val(1), pos(2), embed(3), Wq(4), bq(5), Wk(6), bk(7)
    const float* val   = (const float*)d_in[1];
    const int*   pos   = (const int*)d_in[2];
    const float* embed = (const float*)d_in[3];
    const float* Wq    = (const float*)d_in[4];
    const float* bq    = (const float*)d_in[5];
    const float* Wk    = (const float*)d_in[6];
    const float* bk    = (const float*)d_in[7];
    float* out    = (float*)d_out;
    float* part_s = (float*)d_ws;   // BB*NBLK*DD floats = 128 KB, fully overwritten

    dim3 g(NBLK, BB);   // 512 blocks each
    k_accum<<<g, 256, 0, stream>>>(val, pos, embed, Wq, bq, part_s);
    k_out  <<<g, 256, 0, stream>>>(val, pos, embed, part_s, Wk, bk, out);
}

// Round 9
// 87.621 us; speedup vs baseline: 1.5520x; 1.0007x over previous
//
#include <hip/hip_runtime.h>

#define NN 4096
#define BB 4
#define EE 256
#define DD 64
#define SCALE 0.125f
#define NBLK 128   // blocks per batch row
#define RB 32      // rows per block
#define RW 8       // rows per wave (fully unrolled -> 8 gathers in flight)

// ---------------- Kernel 1 ----------------
// Per block: u_blk[e] = sum_{i in blk} val[i]*embed[pos[i],e]; V_blk = sum val
// Fold Wq here:  part_s[b,blk,d] = sum_e u_blk[e]*Wq[d,e] + bq[d]*V_blk
// (64 floats/block; no atomics; every slot overwritten -> no zero-init)
__global__ __launch_bounds__(256) void k_accum(
        const float* __restrict__ val, const int* __restrict__ pos,
        const float* __restrict__ embed,
        const float* __restrict__ Wq, const float* __restrict__ bq,
        float* __restrict__ part_s) {
    const int b = blockIdx.y, bx = blockIdx.x, t = threadIdx.x;
    const int lane = t & 63, wv = t >> 6, seg = wv;
    const int base = b * NN + bx * RB + wv * RW;

    __shared__ float plds[4][EE];
    __shared__ float vlds[4];
    __shared__ float ps[4][DD];

    float v[RW]; int p[RW];
    #pragma unroll
    for (int r = 0; r < RW; ++r) { v[r] = val[base + r]; p[r] = pos[base + r]; }

    float4 acc = make_float4(0.f, 0.f, 0.f, 0.f);
    float vs = 0.f;
    #pragma unroll
    for (int r = 0; r < RW; ++r) {
        const float4 ev = reinterpret_cast<const float4*>(embed + (size_t)p[r] * EE)[lane];
        acc.x += v[r] * ev.x; acc.y += v[r] * ev.y;
        acc.z += v[r] * ev.z; acc.w += v[r] * ev.w;
        vs += v[r];
    }
    *reinterpret_cast<float4*>(&plds[wv][4 * lane]) = acc;
    if (lane == 0) vlds[wv] = vs;
    __syncthreads();

    // Wq fold directly from the 4 per-wave partials (no uS staging round):
    // thread (seg, d=lane) sums a 64-wide e-segment, float4 LDS loads x4 waves
    {
        const float4* p0 = reinterpret_cast<const float4*>(&plds[0][seg * 64]);
        const float4* p1 = reinterpret_cast<const float4*>(&plds[1][seg * 64]);
        const float4* p2 = reinterpret_cast<const float4*>(&plds[2][seg * 64]);
        const float4* p3 = reinterpret_cast<const float4*>(&plds[3][seg * 64]);
        const float4* wq = reinterpret_cast<const float4*>(Wq + (size_t)lane * EE + seg * 64);
        float a = 0.f;
        #pragma unroll
        for (int q = 0; q < 16; ++q) {
            const float4 x0 = p0[q], x1 = p1[q], x2 = p2[q], x3 = p3[q];
            const float4 y = wq[q];
            a += (x0.x + x1.x + x2.x + x3.x) * y.x
               + (x0.y + x1.y + x2.y + x3.y) * y.y
               + (x0.z + x1.z + x2.z + x3.z) * y.z
               + (x0.w + x1.w + x2.w + x3.w) * y.w;
        }
        ps[seg][lane] = a;
    }
    __syncthreads();
    if (t < DD) {
        const float Vblk = vlds[0] + vlds[1] + vlds[2] + vlds[3];
        part_s[((size_t)b * NBLK + bx) * DD + t] =
            ps[0][t] + ps[1][t] + ps[2][t] + ps[3][t] + bq[t] * Vblk;
    }
}

// ---------------- Kernel 2 ----------------
// Issue embed gathers + val loads into registers FIRST (latency hides under
// the reduce), then: s[d] = sum_blk part_s;  w[e] = sum_d s[d]*Wk[d,e]; c = s.bk
// then: out[b,j] = val[b,j]*(1 + SCALE*(ev[j].w + c))
__global__ __launch_bounds__(256) void k_out(
        const float* __restrict__ val, const int* __restrict__ pos,
        const float* __restrict__ embed,
        const float* __restrict__ part_s,
        const float* __restrict__ Wk, const float* __restrict__ bk,
        float* __restrict__ out) {
    const int b = blockIdx.y, bx = blockIdx.x, t = threadIdx.x;
    const int lane = t & 63, wv = t >> 6, seg = wv;
    const int base = b * NN + bx * RB + wv * RW;

    __shared__ float ps[4][DD];
    __shared__ float sS[DD];
    __shared__ float wsh[EE];
    __shared__ float rowres[RB];
    __shared__ float cSh;

    // ---- issue gathers early; results consumed in phase C ----
    int p[RW];
    #pragma unroll
    for (int r = 0; r < RW; ++r) p[r] = pos[base + r];
    float4 ev[RW];
    #pragma unroll
    for (int r = 0; r < RW; ++r)
        ev[r] = reinterpret_cast<const float4*>(embed + (size_t)p[r] * EE)[lane];
    const float vload = (t < RB) ? val[b * NN + bx * RB + t] : 0.f;

    // ---- A0: reduce part_s -> sS (L2-hot, coalesced within wave) ----
    {
        const float* pp = part_s + ((size_t)b * NBLK + seg * 32) * DD + lane;
        float a = 0.f;
        #pragma unroll 8
        for (int i = 0; i < 32; ++i) a += pp[(size_t)i * DD];
        ps[seg][lane] = a;
    }
    __syncthreads();
    if (t < DD) sS[t] = ps[0][t] + ps[1][t] + ps[2][t] + ps[3][t];
    __syncthreads();

    // ---- B: c (wave 0) and w[e] (all threads, coalesced in t) ----
    if (wv == 0) {
        float x = sS[lane] * bk[lane];
        #pragma unroll
        for (int off = 32; off; off >>= 1) x += __shfl_down(x, off, 64);
        if (lane == 0) cSh = x;
    }
    {
        float a = 0.f;
        #pragma unroll
        for (int d = 0; d < DD; ++d) a += sS[d] * Wk[d * EE + t];
        wsh[t] = a;
    }
    __syncthreads();

    // ---- C: per-row dot from registers, shfl reduce, coalesced store ----
    const float4 wf = reinterpret_cast<const float4*>(wsh)[lane];
    #pragma unroll
    for (int r = 0; r < RW; ++r) {
        float a = ev[r].x * wf.x + ev[r].y * wf.y + ev[r].z * wf.z + ev[r].w * wf.w;
        #pragma unroll
        for (int off = 32; off; off >>= 1) a += __shfl_down(a, off, 64);
        if (lane == 0) rowres[wv * RW + r] = a;
    }
    __syncthreads();
    if (t < RB) {
        const int j = bx * RB + t;
        out[b * NN + j] = vload * (1.f + SCALE * (rowres[t] + cSh));
    }
}

extern "C" void kernel_launch(void* const* d_in, const int* in_sizes, int n_in,
                              void* d_out, int out_size, void* d_ws, size_t ws_size,
                              hipStream_t stream) {
    // inputs: t(0), val(1), pos(2), embed(3), Wq(4), bq(5), Wk(6), bk(7)
    const float* val   = (const float*)d_in[1];
    const int*   pos   = (const int*)d_in[2];
    const float* embed = (const float*)d_in[3];
    const float* Wq    = (const float*)d_in[4];
    const float* bq    = (const float*)d_in[5];
    const float* Wk    = (const float*)d_in[6];
    const float* bk    = (const float*)d_in[7];
    float* out    = (float*)d_out;
    float* part_s = (float*)d_ws;   // BB*NBLK*DD floats = 128 KB, fully overwritten

    dim3 g(NBLK, BB);   // 512 blocks each
    k_accum<<<g, 256, 0, stream>>>(val, pos, embed, Wq, bq, part_s);
    k_out  <<<g, 256, 0, stream>>>(val, pos, embed, part_s, Wk, bk, out);
}